// Round 11
// baseline (122.641 us; speedup 1.0000x reference)
//
#include <hip/hip_runtime.h>
#include <hip/hip_bf16.h>
#include <stdint.h>

// SelfAttention1D: B=8,T=2048,D_IN=512,D_ATTN=8,D_OUT=512, scores=(QK^T)^8, softmax, @V
// k_wvT -> k_fused (QK high-precision with LDS-staged In tile + V bf16 MFMA GEMM,
// 128-key fragment-linear layout) -> k_attn: grid 256 (1 block/CU), 16 waves, 64-row
// q-tiles x 512 cols, K LDS-resident, s^2 exact-max prepass, V register ping-pong
// across barriers (vfA/vfB), P dbuf swizzled.
// Workspace: WvT 512K @0, Q 512K @512K, K 512K @1M, Vg 16M @1.5M (~17.6MB total)

typedef float f32x4_t __attribute__((ext_vector_type(4)));
typedef short s16x8_t __attribute__((ext_vector_type(8)));
typedef unsigned int u32;

static __device__ __forceinline__ unsigned short f2bf(float x){
  union { float f; u32 u; } v; v.f = x;
  return (unsigned short)((v.u + 0x7FFFu + ((v.u >> 16) & 1u)) >> 16);
}

static __device__ __forceinline__ u32 pk2bf(float a, float b){
  __hip_bfloat162 h = __float22bfloat162_rn(float2{a, b});
  union { __hip_bfloat162 h2; u32 u; } c; c.h2 = h;
  return c.u;
}

static __device__ __forceinline__ void gload16(const void* g, void* l){
  __builtin_amdgcn_global_load_lds((const __attribute__((address_space(1))) u32*)g,
                                   (__attribute__((address_space(3))) u32*)l, 16, 0, 0);
}

static __device__ __forceinline__ float dot8(const float* q, const float4& a, const float4& b){
  float s = q[0] * a.x;
  s = fmaf(q[1], a.y, s); s = fmaf(q[2], a.z, s); s = fmaf(q[3], a.w, s);
  s = fmaf(q[4], b.x, s); s = fmaf(q[5], b.y, s); s = fmaf(q[6], b.z, s);
  s = fmaf(q[7], b.w, s);
  return s;
}

// ---------------- K0: W_v [512][512] f32 -> WvT [c][d] bf16 ----------------
__global__ __launch_bounds__(256) void k_wvT(const float* __restrict__ Wv,
                                             unsigned short* __restrict__ WvT){
  __shared__ __align__(16) float tile[64][68];
  const int t = threadIdx.x;
  const int dbase = (blockIdx.x >> 3) * 64;
  const int cbase = (blockIdx.x & 7) * 64;
  {
    const int dl = t >> 2, cq = (t & 3) * 16;
    const float* src = Wv + (size_t)(dbase + dl) * 512 + cbase + cq;
#pragma unroll
    for (int i = 0; i < 16; i += 4){
      float4 v = *(const float4*)(src + i);
      tile[dl][cq + i + 0] = v.x; tile[dl][cq + i + 1] = v.y;
      tile[dl][cq + i + 2] = v.z; tile[dl][cq + i + 3] = v.w;
    }
  }
  __syncthreads();
  const int cl = t >> 2, dq = (t & 3) * 16;
  __align__(16) unsigned short o[16];
#pragma unroll
  for (int i = 0; i < 16; ++i) o[i] = f2bf(tile[dq + i][cl]);
  unsigned short* dst = WvT + (size_t)(cbase + cl) * 512 + dbase + dq;
  *(uint4*)dst = *(const uint4*)o;
  *(uint4*)(dst + 8) = *(const uint4*)(o + 8);
}

// ---------------- k_fused: blocks [0,1024) = Q,K ; blocks [1024,1536) = vproj ----------
// Vg short offset for (b, key, col):
//   b*1048576 + (key>>7)*65536 + (col>>5)*4096 + ((col>>4)&1)*2048 + ((key>>5)&3)*512
//   + (((key>>3)&3)*16 + (col&15))*8 + (key&7)
__global__ __launch_bounds__(256) void k_fused(const float* __restrict__ In,
                                               const float* __restrict__ Wq,
                                               const float* __restrict__ Wk,
                                               const unsigned short* __restrict__ WvT,
                                               float* __restrict__ Qo,
                                               float* __restrict__ Ko,
                                               unsigned short* __restrict__ Vg){
  __shared__ __align__(16) char smem[65536];
  const int t = threadIdx.x;
  if (blockIdx.x < 1024){
    // ---- Q,K high-precision part: stage In[16][512] (32KB) in LDS, W in LDS ----
    float* wt = (float*)smem;                 // 32KB
    float* inT = (float*)(smem + 32768);      // 32KB
    const float* Inb = In + (size_t)blockIdx.x * 16 * 512;
#pragma unroll
    for (int i = 0; i < 8; ++i)
      gload16(Inb + (i * 256 + t) * 4, (char*)inT + (i * 256 + t) * 16);
#pragma unroll
    for (int i = 0; i < 16; i += 4){
      float4 vq = *(const float4*)(Wq + t * 16 + i);
      float4 vk = *(const float4*)(Wk + t * 16 + i);
      const float* pq = &vq.x;
      const float* pk = &vk.x;
#pragma unroll
      for (int j = 0; j < 4; ++j){
        int flat = t * 16 + i + j;
        int d = flat >> 3, f = flat & 7;
        wt[f * 512 + ((((d >> 2) ^ f) << 2) | (d & 3))] = pq[j];
        int fk = f + 8;
        wt[fk * 512 + ((((d >> 2) ^ (fk & 7)) << 2) | (d & 3))] = pk[j];
      }
    }
    __syncthreads();
    const int tokl = t >> 4;
    const int f = t & 15;
    const float* inrow = inT + tokl * 512;    // 16 f-threads broadcast-read same row
    const float* wrow = &wt[f * 512];
    const int swz = f & 7;
    double acc = 0.0;
    for (int cb = 0; cb < 128; cb += 8){
      float part = 0.f;
#pragma unroll
      for (int c = cb; c < cb + 8; ++c){
        float4 x = *(const float4*)(inrow + c * 4);
        float4 ww = *(const float4*)(wrow + ((c ^ swz) << 2));
        part = fmaf(x.x, ww.x, part); part = fmaf(x.y, ww.y, part);
        part = fmaf(x.z, ww.z, part); part = fmaf(x.w, ww.w, part);
      }
      acc += (double)part;
    }
    float r = (float)acc;
    const int tok = (int)blockIdx.x * 16 + tokl;
    if (f < 8) Qo[(size_t)tok * 8 + f] = r;
    else       Ko[(size_t)tok * 8 + (f - 8)] = r;
    return;
  }
  // ---- vproj part: block = keys [mt*128,+128) x cols [nt*128,+128) ----
  char* Ab = smem;
  char* Bb = smem + 16384;
  char* Img = smem + 32768;
  const int vb = (int)blockIdx.x - 1024;
  const int w = t >> 6, lane = t & 63;
  const int mt = vb >> 2, nt = vb & 3;
  const int wm = w >> 1, wn = w & 1;
  const int asub = lane & 3;
  int arow[2], acr[2];
#pragma unroll
  for (int i = 0; i < 2; ++i){
    arow[i] = (w * 2 + i) * 16 + (lane >> 2);
    acr[i]  = asub ^ ((arow[i] >> 1) & 3);
  }
  f32x4_t acc[4][4];
#pragma unroll
  for (int m = 0; m < 4; ++m)
#pragma unroll
    for (int n = 0; n < 4; ++n)
      acc[m][n] = (f32x4_t){0.f, 0.f, 0.f, 0.f};

  auto stageB = [&](int kk, int sel){
#pragma unroll
    for (int i = 0; i < 2; ++i){
      int id = w * 2 + i;
      const unsigned short* gb = WvT + (size_t)(nt * 128 + arow[i]) * 512 + kk * 32 + acr[i] * 8;
      gload16(gb, Bb + sel * 8192 + id * 1024);
    }
  };
  auto loadA = [&](int kk, float4* x, float4* y){
#pragma unroll
    for (int i = 0; i < 2; ++i){
      const float* ga = In + (size_t)(mt * 128 + arow[i]) * 512 + kk * 32 + acr[i] * 8;
      x[i] = *(const float4*)ga;
      y[i] = *(const float4*)(ga + 4);
    }
  };
  auto writeA = [&](const float4* x, const float4* y, int sel){
#pragma unroll
    for (int i = 0; i < 2; ++i){
      __align__(16) unsigned short pk[8] = {
        f2bf(x[i].x), f2bf(x[i].y), f2bf(x[i].z), f2bf(x[i].w),
        f2bf(y[i].x), f2bf(y[i].y), f2bf(y[i].z), f2bf(y[i].w)};
      *(uint4*)(Ab + sel * 8192 + arow[i] * 64 + asub * 16) = *(const uint4*)pk;
    }
  };
  {
    float4 x[2], y[2];
    loadA(0, x, y);
    stageB(0, 0);
    writeA(x, y, 0);
    __syncthreads();
  }
  for (int kk = 0; kk < 16; ++kk){
    const int cur = kk & 1;
    float4 x[2], y[2];
    if (kk < 15){
      loadA(kk + 1, x, y);
      stageB(kk + 1, cur ^ 1);
    }
    s16x8_t a[4], bf[4];
#pragma unroll
    for (int m = 0; m < 4; ++m){
      int row = wm * 64 + m * 16 + (lane & 15);
      int chn = (lane >> 4) ^ ((row >> 1) & 3);
      a[m] = *(const s16x8_t*)(Ab + cur * 8192 + row * 64 + chn * 16);
    }
#pragma unroll
    for (int n = 0; n < 4; ++n){
      int col = wn * 64 + n * 16 + (lane & 15);
      int chn = (lane >> 4) ^ ((col >> 1) & 3);
      bf[n] = *(const s16x8_t*)(Bb + cur * 8192 + col * 64 + chn * 16);
    }
#pragma unroll
    for (int m = 0; m < 4; ++m)
#pragma unroll
      for (int n = 0; n < 4; ++n)
        acc[m][n] = __builtin_amdgcn_mfma_f32_16x16x32_bf16(a[m], bf[n], acc[m][n], 0, 0, 0);
    if (kk < 15) writeA(x, y, cur ^ 1);
    __syncthreads();
  }
  // epilogue: fragment-linear 32KB chunk in LDS, linear copy out
#pragma unroll
  for (int m = 0; m < 4; ++m){
    const int ks2 = (wm * 2 + (m >> 1)) & 3;
    const int hi  = (m * 2 + ((lane >> 4) >> 1)) & 3;
    const int lo0 = ((lane >> 4) & 1) * 4;
#pragma unroll
    for (int n = 0; n < 4; ++n){
      const int g_loc = wn * 2 + (n >> 1);
      const int n2 = n & 1;
      const int cl = lane & 15;
      __align__(8) unsigned short pk2[4];
#pragma unroll
      for (int j = 0; j < 4; ++j) pk2[j] = f2bf(acc[m][n][j]);
      int boff = g_loc * 8192 + n2 * 4096 + ks2 * 1024 + hi * 256 + cl * 16 + lo0 * 2;
      *(uint2*)(Img + boff) = *(const uint2*)pk2;
    }
  }
  __syncthreads();
  const int bq = mt >> 4;
  const int kt = mt & 15;
#pragma unroll
  for (int i = 0; i < 8; ++i){
    int G = i * 256 + t;
    unsigned short* dst = Vg + (size_t)bq * 1048576 + (size_t)kt * 65536
                        + nt * 16384 + G * 8;
    *(uint4*)dst = *(const uint4*)(Img + G * 16);
  }
}

// ---------------- k_attn: 64-row x 512-col blocks, grid 256 (1/CU), 16 waves ----------------
// b = bid&7 (XCD pin), qt = bid>>3 (32 tiles of 64 rows). lane = q-row; wave g in [0,16)
// scores keys [8g,8g+8) per 128-key tile and owns V cols [g*32,(g+1)*32) as register
// fragments, ping-ponged (vfA/vfB) across barriers so L2 latency hides under score.
__global__ __launch_bounds__(1024) void k_attn(const float* __restrict__ Qg,
                                               const float* __restrict__ Kg,
                                               const unsigned short* __restrict__ Vg,
                                               float* __restrict__ Out){
  __shared__ __align__(16) char smem[102656];
  // Klds 64KB @0 ; Pb dbuf 2x16KB @65536 ; red 4KB @98304 ; fin 256B @102400
  // epilogue img [16][520] f32 @0 overlays Klds
  const int t = threadIdx.x;
  const int g = t >> 6, lane = t & 63;     // lane = q-row
  const int b = blockIdx.x & 7;
  const int qt = blockIdx.x >> 3;
  const int qbase = qt * 64;

  float qreg[8];
  {
    const float* Qp = Qg + (size_t)(b * 2048 + qbase + lane) * 8;
    float4 a = *(const float4*)Qp;
    float4 c = *(const float4*)(Qp + 4);
    qreg[0] = a.x; qreg[1] = a.y; qreg[2] = a.z; qreg[3] = a.w;
    qreg[4] = c.x; qreg[5] = c.y; qreg[6] = c.z; qreg[7] = c.w;
  }
  const float* Kp = Kg + (size_t)b * (2048 * 8);
  const unsigned short* Vb = Vg + (size_t)b * 1048576;
  char* Klds = smem;
  char* Pb = smem + 65536;
  float* red = (float*)(smem + 98304);
  float* fin = (float*)(smem + 102400);

  // ---- stage ALL of K (64KB) once ----
#pragma unroll
  for (int i = 0; i < 4; ++i)
    gload16(Kp + (size_t)(i * 1024 + t) * 4, Klds + (i * 1024 + t) * 16);
  __syncthreads();

  // ---- prepass: exact row max of s^2 (p = (s^2)^4, same rounding path), pure VALU ----
  float amax2 = 0.f;
  {
    const float* kbase = (const float*)Klds + (g * 8) * 8;
#pragma unroll 2
    for (int tt = 0; tt < 16; ++tt){
      const float* kb = kbase + tt * 1024;
#pragma unroll
      for (int j = 0; j < 8; ++j){
        float4 k0 = *(const float4*)(kb + j * 8);
        float4 k1 = *(const float4*)(kb + j * 8 + 4);
        float s = dot8(qreg, k0, k1);
        amax2 = fmaxf(amax2, s * s);
      }
    }
  }
  red[g * 64 + lane] = amax2;
  __syncthreads();
  float am = red[lane];
#pragma unroll
  for (int s = 1; s < 16; ++s) am = fmaxf(am, red[s * 64 + lane]);
  float mreg;
  { float s4 = am * am; mreg = s4 * s4; }
  const float LOG2E = 1.44269504f;
  const float me2 = mreg * LOG2E;
  float lp = 0.f;

  const int pswz = ((g ^ (lane & 15)) << 4);
  auto score = [&](int tt, int sel){
    const float* kb = (const float*)Klds + (tt * 128 + g * 8) * 8;
    float es[8];
#pragma unroll
    for (int j = 0; j < 8; ++j){
      float4 k0 = *(const float4*)(kb + j * 8);
      float4 k1 = *(const float4*)(kb + j * 8 + 4);
      float s = dot8(qreg, k0, k1);
      float s2 = s * s; float s4 = s2 * s2; float p = s4 * s4;
      es[j] = exp2f(fmaf(p, LOG2E, -me2));
      lp += es[j];
    }
    uint4 pkd;
    pkd.x = pk2bf(es[0], es[1]); pkd.y = pk2bf(es[2], es[3]);
    pkd.z = pk2bf(es[4], es[5]); pkd.w = pk2bf(es[6], es[7]);
    *(uint4*)(Pb + sel * 16384 + lane * 256 + pswz) = pkd;
  };

  auto vload = [&](int tt, s16x8_t vf[2][4]){
    const unsigned short* vb = Vb + (size_t)tt * 65536 + g * 4096 + lane * 8;
#pragma unroll
    for (int n = 0; n < 2; ++n)
#pragma unroll
      for (int ks = 0; ks < 4; ++ks)
        vf[n][ks] = *(const s16x8_t*)(vb + n * 2048 + ks * 512);
  };

  f32x4_t acc[4][2];
#pragma unroll
  for (int mm = 0; mm < 4; ++mm)
#pragma unroll
    for (int n = 0; n < 2; ++n)
      acc[mm][n] = (f32x4_t){0.f, 0.f, 0.f, 0.f};

  auto mfma_tile = [&](int sel, s16x8_t vf[2][4]){
#pragma unroll
    for (int ks = 0; ks < 4; ++ks){
      s16x8_t a[4];
#pragma unroll
      for (int mm = 0; mm < 4; ++mm){
        int r = mm * 16 + (lane & 15);
        int slot = (ks * 4 + (lane >> 4)) ^ (r & 15);
        a[mm] = *(const s16x8_t*)(Pb + sel * 16384 + r * 256 + (slot << 4));
      }
      __builtin_amdgcn_s_setprio(1);
#pragma unroll
      for (int mm = 0; mm < 4; ++mm)
#pragma unroll
        for (int n = 0; n < 2; ++n)
          acc[mm][n] = __builtin_amdgcn_mfma_f32_16x16x32_bf16(a[mm], vf[n][ks], acc[mm][n], 0, 0, 0);
      __builtin_amdgcn_s_setprio(0);
    }
  };

  // prologue: P(0), V(0)
  score(0, 0);
  s16x8_t vfA[2][4], vfB[2][4];
  vload(0, vfA);
  __syncthreads();

  // main loop: 8 double-iterations, V ping-pong carried across barriers
  for (int it = 0; it < 8; ++it){
    const int t0 = it * 2, t1 = it * 2 + 1;
    // tile t0 (P[0], vfA); prefetch V(t1) into vfB
    vload(t1, vfB);
    if (t0 + 1 < 16) score(t0 + 1, 1);
    mfma_tile(0, vfA);
    __syncthreads();
    // tile t1 (P[1], vfB); prefetch V(t1+1) into vfA
    if (t1 + 1 < 16){
      vload(t1 + 1, vfA);
      score(t1 + 1, 0);
    }
    mfma_tile(1, vfB);
    __syncthreads();
  }

  // ---- softmax denominator ----
  red[g * 64 + lane] = lp;
  __syncthreads();
  if (t < 64){
    float s = red[t];
#pragma unroll
    for (int s2 = 1; s2 < 16; ++s2) s += red[s2 * 64 + t];
    fin[t] = 1.f / s;
  }
  __syncthreads();

  // ---- epilogue: 4 rounds of 16 rows x 512 cols via LDS transpose (img overlays Klds) ----
  float* img = (float*)smem;
#pragma unroll
  for (int mm = 0; mm < 4; ++mm){
    float linv[4];
#pragma unroll
    for (int j = 0; j < 4; ++j)
      linv[j] = fin[mm * 16 + ((lane >> 4) << 2) + j];
#pragma unroll
    for (int n = 0; n < 2; ++n){
      int colL = g * 32 + n * 16 + (lane & 15);
#pragma unroll
      for (int j = 0; j < 4; ++j){
        int r16 = ((lane >> 4) << 2) + j;
        img[r16 * 520 + colL] = acc[mm][n][j] * linv[j];
      }
    }
    __syncthreads();
#pragma unroll
    for (int i = 0; i < 2; ++i){
      int f4 = i * 1024 + t;
      int r16 = f4 >> 7, c4 = f4 & 127;
      float4 v = *(const float4*)(img + r16 * 520 + c4 * 4);
      *(float4*)(Out + (size_t)(b * 2048 + qbase + mm * 16 + r16) * 512 + c4 * 4) = v;
    }
    __syncthreads();
  }
}

extern "C" void kernel_launch(void* const* d_in, const int* in_sizes, int n_in,
                              void* d_out, int out_size, void* d_ws, size_t ws_size,
                              hipStream_t stream){
  const float* In = (const float*)d_in[0];
  const float* Wq = (const float*)d_in[1];
  const float* Wk = (const float*)d_in[2];
  const float* Wv = (const float*)d_in[3];
  // power (d_in[4]) is the constant 8; hardcoded as three squarings.
  char* ws = (char*)d_ws;
  unsigned short* WvT = (unsigned short*)(ws);
  float* Q            = (float*)(ws + 524288);
  float* K            = (float*)(ws + 1048576);
  unsigned short* Vg  = (unsigned short*)(ws + 1572864);
  float* Out = (float*)d_out;

  hipLaunchKernelGGL(k_wvT,   dim3(64),   dim3(256),  0, stream, Wv, WvT);
  hipLaunchKernelGGL(k_fused, dim3(1536), dim3(256),  0, stream, In, Wq, Wk, WvT, Q, K, Vg);
  hipLaunchKernelGGL(k_attn,  dim3(256),  dim3(1024), 0, stream, Q, K, Vg, Out);
}

// Round 12
// 118.027 us; speedup vs baseline: 1.0391x; 1.0391x over previous
//
#include <hip/hip_runtime.h>
#include <hip/hip_bf16.h>
#include <stdint.h>

// SelfAttention1D: B=8,T=2048,D_IN=512,D_ATTN=8,D_OUT=512, scores=(QK^T)^8, softmax, @V
// k_wvT -> k_fused (QK high-precision with LDS-staged In tile + V bf16 MFMA GEMM,
// 128-key fragment-linear layout) -> k_attn: grid 256 (1 block/CU), 16 waves,
// __launch_bounds__(1024,4) => 128 VGPRs (spill fix for the V register ping-pong),
// 64-row q-tiles x 512 cols, K LDS-resident, s^2 exact-max prepass, vfA/vfB ping-pong.
// Workspace: WvT 512K @0, Q 512K @512K, K 512K @1M, Vg 16M @1.5M (~17.6MB total)

typedef float f32x4_t __attribute__((ext_vector_type(4)));
typedef short s16x8_t __attribute__((ext_vector_type(8)));
typedef unsigned int u32;

static __device__ __forceinline__ unsigned short f2bf(float x){
  union { float f; u32 u; } v; v.f = x;
  return (unsigned short)((v.u + 0x7FFFu + ((v.u >> 16) & 1u)) >> 16);
}

static __device__ __forceinline__ u32 pk2bf(float a, float b){
  __hip_bfloat162 h = __float22bfloat162_rn(float2{a, b});
  union { __hip_bfloat162 h2; u32 u; } c; c.h2 = h;
  return c.u;
}

static __device__ __forceinline__ void gload16(const void* g, void* l){
  __builtin_amdgcn_global_load_lds((const __attribute__((address_space(1))) u32*)g,
                                   (__attribute__((address_space(3))) u32*)l, 16, 0, 0);
}

static __device__ __forceinline__ float dot8(const float* q, const float4& a, const float4& b){
  float s = q[0] * a.x;
  s = fmaf(q[1], a.y, s); s = fmaf(q[2], a.z, s); s = fmaf(q[3], a.w, s);
  s = fmaf(q[4], b.x, s); s = fmaf(q[5], b.y, s); s = fmaf(q[6], b.z, s);
  s = fmaf(q[7], b.w, s);
  return s;
}

// ---------------- K0: W_v [512][512] f32 -> WvT [c][d] bf16 ----------------
__global__ __launch_bounds__(256) void k_wvT(const float* __restrict__ Wv,
                                             unsigned short* __restrict__ WvT){
  __shared__ __align__(16) float tile[64][68];
  const int t = threadIdx.x;
  const int dbase = (blockIdx.x >> 3) * 64;
  const int cbase = (blockIdx.x & 7) * 64;
  {
    const int dl = t >> 2, cq = (t & 3) * 16;
    const float* src = Wv + (size_t)(dbase + dl) * 512 + cbase + cq;
#pragma unroll
    for (int i = 0; i < 16; i += 4){
      float4 v = *(const float4*)(src + i);
      tile[dl][cq + i + 0] = v.x; tile[dl][cq + i + 1] = v.y;
      tile[dl][cq + i + 2] = v.z; tile[dl][cq + i + 3] = v.w;
    }
  }
  __syncthreads();
  const int cl = t >> 2, dq = (t & 3) * 16;
  __align__(16) unsigned short o[16];
#pragma unroll
  for (int i = 0; i < 16; ++i) o[i] = f2bf(tile[dq + i][cl]);
  unsigned short* dst = WvT + (size_t)(cbase + cl) * 512 + dbase + dq;
  *(uint4*)dst = *(const uint4*)o;
  *(uint4*)(dst + 8) = *(const uint4*)(o + 8);
}

// ---------------- k_fused: blocks [0,1024) = Q,K ; blocks [1024,1536) = vproj ----------
// Vg short offset for (b, key, col):
//   b*1048576 + (key>>7)*65536 + (col>>5)*4096 + ((col>>4)&1)*2048 + ((key>>5)&3)*512
//   + (((key>>3)&3)*16 + (col&15))*8 + (key&7)
__global__ __launch_bounds__(256) void k_fused(const float* __restrict__ In,
                                               const float* __restrict__ Wq,
                                               const float* __restrict__ Wk,
                                               const unsigned short* __restrict__ WvT,
                                               float* __restrict__ Qo,
                                               float* __restrict__ Ko,
                                               unsigned short* __restrict__ Vg){
  __shared__ __align__(16) char smem[65536];
  const int t = threadIdx.x;
  if (blockIdx.x < 1024){
    // ---- Q,K high-precision part: stage In[16][512] (32KB) in LDS, W in LDS ----
    float* wt = (float*)smem;                 // 32KB
    float* inT = (float*)(smem + 32768);      // 32KB
    const float* Inb = In + (size_t)blockIdx.x * 16 * 512;
#pragma unroll
    for (int i = 0; i < 8; ++i)
      gload16(Inb + (i * 256 + t) * 4, (char*)inT + (i * 256 + t) * 16);
#pragma unroll
    for (int i = 0; i < 16; i += 4){
      float4 vq = *(const float4*)(Wq + t * 16 + i);
      float4 vk = *(const float4*)(Wk + t * 16 + i);
      const float* pq = &vq.x;
      const float* pk = &vk.x;
#pragma unroll
      for (int j = 0; j < 4; ++j){
        int flat = t * 16 + i + j;
        int d = flat >> 3, f = flat & 7;
        wt[f * 512 + ((((d >> 2) ^ f) << 2) | (d & 3))] = pq[j];
        int fk = f + 8;
        wt[fk * 512 + ((((d >> 2) ^ (fk & 7)) << 2) | (d & 3))] = pk[j];
      }
    }
    __syncthreads();
    const int tokl = t >> 4;
    const int f = t & 15;
    const float* inrow = inT + tokl * 512;    // 16 f-threads broadcast-read same row
    const float* wrow = &wt[f * 512];
    const int swz = f & 7;
    double acc = 0.0;
    for (int cb = 0; cb < 128; cb += 8){
      float part = 0.f;
#pragma unroll
      for (int c = cb; c < cb + 8; ++c){
        float4 x = *(const float4*)(inrow + c * 4);
        float4 ww = *(const float4*)(wrow + ((c ^ swz) << 2));
        part = fmaf(x.x, ww.x, part); part = fmaf(x.y, ww.y, part);
        part = fmaf(x.z, ww.z, part); part = fmaf(x.w, ww.w, part);
      }
      acc += (double)part;
    }
    float r = (float)acc;
    const int tok = (int)blockIdx.x * 16 + tokl;
    if (f < 8) Qo[(size_t)tok * 8 + f] = r;
    else       Ko[(size_t)tok * 8 + (f - 8)] = r;
    return;
  }
  // ---- vproj part: block = keys [mt*128,+128) x cols [nt*128,+128) ----
  char* Ab = smem;
  char* Bb = smem + 16384;
  char* Img = smem + 32768;
  const int vb = (int)blockIdx.x - 1024;
  const int w = t >> 6, lane = t & 63;
  const int mt = vb >> 2, nt = vb & 3;
  const int wm = w >> 1, wn = w & 1;
  const int asub = lane & 3;
  int arow[2], acr[2];
#pragma unroll
  for (int i = 0; i < 2; ++i){
    arow[i] = (w * 2 + i) * 16 + (lane >> 2);
    acr[i]  = asub ^ ((arow[i] >> 1) & 3);
  }
  f32x4_t acc[4][4];
#pragma unroll
  for (int m = 0; m < 4; ++m)
#pragma unroll
    for (int n = 0; n < 4; ++n)
      acc[m][n] = (f32x4_t){0.f, 0.f, 0.f, 0.f};

  auto stageB = [&](int kk, int sel){
#pragma unroll
    for (int i = 0; i < 2; ++i){
      int id = w * 2 + i;
      const unsigned short* gb = WvT + (size_t)(nt * 128 + arow[i]) * 512 + kk * 32 + acr[i] * 8;
      gload16(gb, Bb + sel * 8192 + id * 1024);
    }
  };
  auto loadA = [&](int kk, float4* x, float4* y){
#pragma unroll
    for (int i = 0; i < 2; ++i){
      const float* ga = In + (size_t)(mt * 128 + arow[i]) * 512 + kk * 32 + acr[i] * 8;
      x[i] = *(const float4*)ga;
      y[i] = *(const float4*)(ga + 4);
    }
  };
  auto writeA = [&](const float4* x, const float4* y, int sel){
#pragma unroll
    for (int i = 0; i < 2; ++i){
      __align__(16) unsigned short pk[8] = {
        f2bf(x[i].x), f2bf(x[i].y), f2bf(x[i].z), f2bf(x[i].w),
        f2bf(y[i].x), f2bf(y[i].y), f2bf(y[i].z), f2bf(y[i].w)};
      *(uint4*)(Ab + sel * 8192 + arow[i] * 64 + asub * 16) = *(const uint4*)pk;
    }
  };
  {
    float4 x[2], y[2];
    loadA(0, x, y);
    stageB(0, 0);
    writeA(x, y, 0);
    __syncthreads();
  }
  for (int kk = 0; kk < 16; ++kk){
    const int cur = kk & 1;
    float4 x[2], y[2];
    if (kk < 15){
      loadA(kk + 1, x, y);
      stageB(kk + 1, cur ^ 1);
    }
    s16x8_t a[4], bf[4];
#pragma unroll
    for (int m = 0; m < 4; ++m){
      int row = wm * 64 + m * 16 + (lane & 15);
      int chn = (lane >> 4) ^ ((row >> 1) & 3);
      a[m] = *(const s16x8_t*)(Ab + cur * 8192 + row * 64 + chn * 16);
    }
#pragma unroll
    for (int n = 0; n < 4; ++n){
      int col = wn * 64 + n * 16 + (lane & 15);
      int chn = (lane >> 4) ^ ((col >> 1) & 3);
      bf[n] = *(const s16x8_t*)(Bb + cur * 8192 + col * 64 + chn * 16);
    }
#pragma unroll
    for (int m = 0; m < 4; ++m)
#pragma unroll
      for (int n = 0; n < 4; ++n)
        acc[m][n] = __builtin_amdgcn_mfma_f32_16x16x32_bf16(a[m], bf[n], acc[m][n], 0, 0, 0);
    if (kk < 15) writeA(x, y, cur ^ 1);
    __syncthreads();
  }
  // epilogue: fragment-linear 32KB chunk in LDS, linear copy out
#pragma unroll
  for (int m = 0; m < 4; ++m){
    const int ks2 = (wm * 2 + (m >> 1)) & 3;
    const int hi  = (m * 2 + ((lane >> 4) >> 1)) & 3;
    const int lo0 = ((lane >> 4) & 1) * 4;
#pragma unroll
    for (int n = 0; n < 4; ++n){
      const int g_loc = wn * 2 + (n >> 1);
      const int n2 = n & 1;
      const int cl = lane & 15;
      __align__(8) unsigned short pk2[4];
#pragma unroll
      for (int j = 0; j < 4; ++j) pk2[j] = f2bf(acc[m][n][j]);
      int boff = g_loc * 8192 + n2 * 4096 + ks2 * 1024 + hi * 256 + cl * 16 + lo0 * 2;
      *(uint2*)(Img + boff) = *(const uint2*)pk2;
    }
  }
  __syncthreads();
  const int bq = mt >> 4;
  const int kt = mt & 15;
#pragma unroll
  for (int i = 0; i < 8; ++i){
    int G = i * 256 + t;
    unsigned short* dst = Vg + (size_t)bq * 1048576 + (size_t)kt * 65536
                        + nt * 16384 + G * 8;
    *(uint4*)dst = *(const uint4*)(Img + G * 16);
  }
}

// ---------------- k_attn: 64-row x 512-col blocks, grid 256 (1/CU), 16 waves ----------------
// __launch_bounds__(1024,4): 4 waves/EU => VGPR cap 128 (ping-pong fits in registers).
__global__ __launch_bounds__(1024, 4) void k_attn(const float* __restrict__ Qg,
                                                  const float* __restrict__ Kg,
                                                  const unsigned short* __restrict__ Vg,
                                                  float* __restrict__ Out){
  __shared__ __align__(16) char smem[102656];
  // Klds 64KB @0 ; Pb dbuf 2x16KB @65536 ; red 4KB @98304 ; fin 256B @102400
  // epilogue img [16][520] f32 @0 overlays Klds
  const int t = threadIdx.x;
  const int g = t >> 6, lane = t & 63;     // lane = q-row
  const int b = blockIdx.x & 7;
  const int qt = blockIdx.x >> 3;
  const int qbase = qt * 64;

  float qreg[8];
  {
    const float* Qp = Qg + (size_t)(b * 2048 + qbase + lane) * 8;
    float4 a = *(const float4*)Qp;
    float4 c = *(const float4*)(Qp + 4);
    qreg[0] = a.x; qreg[1] = a.y; qreg[2] = a.z; qreg[3] = a.w;
    qreg[4] = c.x; qreg[5] = c.y; qreg[6] = c.z; qreg[7] = c.w;
  }
  const float* Kp = Kg + (size_t)b * (2048 * 8);
  const unsigned short* Vb = Vg + (size_t)b * 1048576;
  char* Klds = smem;
  char* Pb = smem + 65536;
  float* red = (float*)(smem + 98304);
  float* fin = (float*)(smem + 102400);

  // ---- stage ALL of K (64KB) once ----
#pragma unroll
  for (int i = 0; i < 4; ++i)
    gload16(Kp + (size_t)(i * 1024 + t) * 4, Klds + (i * 1024 + t) * 16);
  __syncthreads();

  // ---- prepass: exact row max of s^2 (p = (s^2)^4, same rounding path), pure VALU ----
  float amax2 = 0.f;
  {
    const float* kbase = (const float*)Klds + (g * 8) * 8;
#pragma unroll 2
    for (int tt = 0; tt < 16; ++tt){
      const float* kb = kbase + tt * 1024;
#pragma unroll
      for (int j = 0; j < 8; ++j){
        float4 k0 = *(const float4*)(kb + j * 8);
        float4 k1 = *(const float4*)(kb + j * 8 + 4);
        float s = dot8(qreg, k0, k1);
        amax2 = fmaxf(amax2, s * s);
      }
    }
  }
  red[g * 64 + lane] = amax2;
  __syncthreads();
  float am = red[lane];
#pragma unroll
  for (int s = 1; s < 16; ++s) am = fmaxf(am, red[s * 64 + lane]);
  float mreg;
  { float s4 = am * am; mreg = s4 * s4; }
  const float LOG2E = 1.44269504f;
  const float me2 = mreg * LOG2E;
  float lp = 0.f;

  const int pswz = ((g ^ (lane & 15)) << 4);
  auto score = [&](int tt, int sel){
    const float* kb = (const float*)Klds + (tt * 128 + g * 8) * 8;
    uint4 pkd;
    u32* pw = &pkd.x;
#pragma unroll
    for (int jp = 0; jp < 4; ++jp){
      float e0, e1;
#pragma unroll
      for (int h = 0; h < 2; ++h){
        const int j = jp * 2 + h;
        float4 k0 = *(const float4*)(kb + j * 8);
        float4 k1 = *(const float4*)(kb + j * 8 + 4);
        float s = dot8(qreg, k0, k1);
        float s2 = s * s; float s4 = s2 * s2; float p = s4 * s4;
        float e = __builtin_amdgcn_exp2f(fmaf(p, LOG2E, -me2));
        lp += e;
        if (h == 0) e0 = e; else e1 = e;
      }
      pw[jp] = pk2bf(e0, e1);
    }
    *(uint4*)(Pb + sel * 16384 + lane * 256 + pswz) = pkd;
  };

  auto vload = [&](int tt, s16x8_t vf[2][4]){
    const unsigned short* vb = Vb + (size_t)tt * 65536 + g * 4096 + lane * 8;
#pragma unroll
    for (int n = 0; n < 2; ++n)
#pragma unroll
      for (int ks = 0; ks < 4; ++ks)
        vf[n][ks] = *(const s16x8_t*)(vb + n * 2048 + ks * 512);
  };

  f32x4_t acc[4][2];
#pragma unroll
  for (int mm = 0; mm < 4; ++mm)
#pragma unroll
    for (int n = 0; n < 2; ++n)
      acc[mm][n] = (f32x4_t){0.f, 0.f, 0.f, 0.f};

  auto mfma_tile = [&](int sel, s16x8_t vf[2][4]){
#pragma unroll
    for (int ks = 0; ks < 4; ++ks){
      s16x8_t a[4];
#pragma unroll
      for (int mm = 0; mm < 4; ++mm){
        int r = mm * 16 + (lane & 15);
        int slot = (ks * 4 + (lane >> 4)) ^ (r & 15);
        a[mm] = *(const s16x8_t*)(Pb + sel * 16384 + r * 256 + (slot << 4));
      }
      __builtin_amdgcn_s_setprio(1);
#pragma unroll
      for (int mm = 0; mm < 4; ++mm)
#pragma unroll
        for (int n = 0; n < 2; ++n)
          acc[mm][n] = __builtin_amdgcn_mfma_f32_16x16x32_bf16(a[mm], vf[n][ks], acc[mm][n], 0, 0, 0);
      __builtin_amdgcn_s_setprio(0);
    }
  };

  // prologue: P(0), V(0)
  score(0, 0);
  s16x8_t vfA[2][4], vfB[2][4];
  vload(0, vfA);
  __syncthreads();

  // main loop: 8 double-iterations, V ping-pong carried across barriers (in registers)
  for (int it = 0; it < 8; ++it){
    const int t0 = it * 2, t1 = it * 2 + 1;
    vload(t1, vfB);
    if (t0 + 1 < 16) score(t0 + 1, 1);
    mfma_tile(0, vfA);
    __syncthreads();
    if (t1 + 1 < 16){
      vload(t1 + 1, vfA);
      score(t1 + 1, 0);
    }
    mfma_tile(1, vfB);
    __syncthreads();
  }

  // ---- softmax denominator ----
  red[g * 64 + lane] = lp;
  __syncthreads();
  if (t < 64){
    float s = red[t];
#pragma unroll
    for (int s2 = 1; s2 < 16; ++s2) s += red[s2 * 64 + t];
    fin[t] = 1.f / s;
  }
  __syncthreads();

  // ---- epilogue: 4 rounds of 16 rows x 512 cols via LDS transpose (img overlays Klds) ----
  float* img = (float*)smem;
#pragma unroll
  for (int mm = 0; mm < 4; ++mm){
    float linv[4];
#pragma unroll
    for (int j = 0; j < 4; ++j)
      linv[j] = fin[mm * 16 + ((lane >> 4) << 2) + j];
#pragma unroll
    for (int n = 0; n < 2; ++n){
      int colL = g * 32 + n * 16 + (lane & 15);
#pragma unroll
      for (int j = 0; j < 4; ++j){
        int r16 = ((lane >> 4) << 2) + j;
        img[r16 * 520 + colL] = acc[mm][n][j] * linv[j];
      }
    }
    __syncthreads();
#pragma unroll
    for (int i = 0; i < 2; ++i){
      int f4 = i * 1024 + t;
      int r16 = f4 >> 7, c4 = f4 & 127;
      float4 v = *(const float4*)(img + r16 * 520 + c4 * 4);
      *(float4*)(Out + (size_t)(b * 2048 + qbase + mm * 16 + r16) * 512 + c4 * 4) = v;
    }
    __syncthreads();
  }
}

extern "C" void kernel_launch(void* const* d_in, const int* in_sizes, int n_in,
                              void* d_out, int out_size, void* d_ws, size_t ws_size,
                              hipStream_t stream){
  const float* In = (const float*)d_in[0];
  const float* Wq = (const float*)d_in[1];
  const float* Wk = (const float*)d_in[2];
  const float* Wv = (const float*)d_in[3];
  // power (d_in[4]) is the constant 8; hardcoded as three squarings.
  char* ws = (char*)d_ws;
  unsigned short* WvT = (unsigned short*)(ws);
  float* Q            = (float*)(ws + 524288);
  float* K            = (float*)(ws + 1048576);
  unsigned short* Vg  = (unsigned short*)(ws + 1572864);
  float* Out = (float*)d_out;

  hipLaunchKernelGGL(k_wvT,   dim3(64),   dim3(256),  0, stream, Wv, WvT);
  hipLaunchKernelGGL(k_fused, dim3(1536), dim3(256),  0, stream, In, Wq, Wk, WvT, Q, K, Vg);
  hipLaunchKernelGGL(k_attn,  dim3(256),  dim3(1024), 0, stream, Q, K, Vg, Out);
}

// Round 13
// 99.168 us; speedup vs baseline: 1.2367x; 1.1902x over previous
//
#include <hip/hip_runtime.h>
#include <hip/hip_bf16.h>
#include <stdint.h>

// SelfAttention1D: B=8,T=2048,D_IN=512,D_ATTN=8,D_OUT=512, scores=(QK^T)^8, softmax, @V
// k_wvT -> k_fused (QK high-precision with LDS-staged In tile + V bf16 MFMA GEMM,
// 128-key fragment-linear layout) -> k_attn: grid 256 (1 block/CU), 16 waves, 64-row
// q-tiles x 512 cols, K LDS-resident, s^2 exact-max prepass, SINGLE V fragment set
// (no spill: VGPR 64 + AGPR 32), score/MFMA interleaved per ks-slice for pipe overlap.
// Workspace: WvT 512K @0, Q 512K @512K, K 512K @1M, Vg 16M @1.5M (~17.6MB total)

typedef float f32x4_t __attribute__((ext_vector_type(4)));
typedef short s16x8_t __attribute__((ext_vector_type(8)));
typedef unsigned int u32;

static __device__ __forceinline__ unsigned short f2bf(float x){
  union { float f; u32 u; } v; v.f = x;
  return (unsigned short)((v.u + 0x7FFFu + ((v.u >> 16) & 1u)) >> 16);
}

static __device__ __forceinline__ u32 pk2bf(float a, float b){
  __hip_bfloat162 h = __float22bfloat162_rn(float2{a, b});
  union { __hip_bfloat162 h2; u32 u; } c; c.h2 = h;
  return c.u;
}

static __device__ __forceinline__ void gload16(const void* g, void* l){
  __builtin_amdgcn_global_load_lds((const __attribute__((address_space(1))) u32*)g,
                                   (__attribute__((address_space(3))) u32*)l, 16, 0, 0);
}

static __device__ __forceinline__ float dot8(const float* q, const float4& a, const float4& b){
  float s = q[0] * a.x;
  s = fmaf(q[1], a.y, s); s = fmaf(q[2], a.z, s); s = fmaf(q[3], a.w, s);
  s = fmaf(q[4], b.x, s); s = fmaf(q[5], b.y, s); s = fmaf(q[6], b.z, s);
  s = fmaf(q[7], b.w, s);
  return s;
}

// ---------------- K0: W_v [512][512] f32 -> WvT [c][d] bf16 ----------------
__global__ __launch_bounds__(256) void k_wvT(const float* __restrict__ Wv,
                                             unsigned short* __restrict__ WvT){
  __shared__ __align__(16) float tile[64][68];
  const int t = threadIdx.x;
  const int dbase = (blockIdx.x >> 3) * 64;
  const int cbase = (blockIdx.x & 7) * 64;
  {
    const int dl = t >> 2, cq = (t & 3) * 16;
    const float* src = Wv + (size_t)(dbase + dl) * 512 + cbase + cq;
#pragma unroll
    for (int i = 0; i < 16; i += 4){
      float4 v = *(const float4*)(src + i);
      tile[dl][cq + i + 0] = v.x; tile[dl][cq + i + 1] = v.y;
      tile[dl][cq + i + 2] = v.z; tile[dl][cq + i + 3] = v.w;
    }
  }
  __syncthreads();
  const int cl = t >> 2, dq = (t & 3) * 16;
  __align__(16) unsigned short o[16];
#pragma unroll
  for (int i = 0; i < 16; ++i) o[i] = f2bf(tile[dq + i][cl]);
  unsigned short* dst = WvT + (size_t)(cbase + cl) * 512 + dbase + dq;
  *(uint4*)dst = *(const uint4*)o;
  *(uint4*)(dst + 8) = *(const uint4*)(o + 8);
}

// ---------------- k_fused: blocks [0,1024) = Q,K ; blocks [1024,1536) = vproj ----------
// Vg short offset for (b, key, col):
//   b*1048576 + (key>>7)*65536 + (col>>5)*4096 + ((col>>4)&1)*2048 + ((key>>5)&3)*512
//   + (((key>>3)&3)*16 + (col&15))*8 + (key&7)
__global__ __launch_bounds__(256) void k_fused(const float* __restrict__ In,
                                               const float* __restrict__ Wq,
                                               const float* __restrict__ Wk,
                                               const unsigned short* __restrict__ WvT,
                                               float* __restrict__ Qo,
                                               float* __restrict__ Ko,
                                               unsigned short* __restrict__ Vg){
  __shared__ __align__(16) char smem[65536];
  const int t = threadIdx.x;
  if (blockIdx.x < 1024){
    // ---- Q,K high-precision part: stage In[16][512] (32KB) in LDS, W in LDS ----
    float* wt = (float*)smem;                 // 32KB
    float* inT = (float*)(smem + 32768);      // 32KB
    const float* Inb = In + (size_t)blockIdx.x * 16 * 512;
#pragma unroll
    for (int i = 0; i < 8; ++i)
      gload16(Inb + (i * 256 + t) * 4, (char*)inT + (i * 256 + t) * 16);
#pragma unroll
    for (int i = 0; i < 16; i += 4){
      float4 vq = *(const float4*)(Wq + t * 16 + i);
      float4 vk = *(const float4*)(Wk + t * 16 + i);
      const float* pq = &vq.x;
      const float* pk = &vk.x;
#pragma unroll
      for (int j = 0; j < 4; ++j){
        int flat = t * 16 + i + j;
        int d = flat >> 3, f = flat & 7;
        wt[f * 512 + ((((d >> 2) ^ f) << 2) | (d & 3))] = pq[j];
        int fk = f + 8;
        wt[fk * 512 + ((((d >> 2) ^ (fk & 7)) << 2) | (d & 3))] = pk[j];
      }
    }
    __syncthreads();
    const int tokl = t >> 4;
    const int f = t & 15;
    const float* inrow = inT + tokl * 512;    // 16 f-threads broadcast-read same row
    const float* wrow = &wt[f * 512];
    const int swz = f & 7;
    double acc = 0.0;
    for (int cb = 0; cb < 128; cb += 8){
      float part = 0.f;
#pragma unroll
      for (int c = cb; c < cb + 8; ++c){
        float4 x = *(const float4*)(inrow + c * 4);
        float4 ww = *(const float4*)(wrow + ((c ^ swz) << 2));
        part = fmaf(x.x, ww.x, part); part = fmaf(x.y, ww.y, part);
        part = fmaf(x.z, ww.z, part); part = fmaf(x.w, ww.w, part);
      }
      acc += (double)part;
    }
    float r = (float)acc;
    const int tok = (int)blockIdx.x * 16 + tokl;
    if (f < 8) Qo[(size_t)tok * 8 + f] = r;
    else       Ko[(size_t)tok * 8 + (f - 8)] = r;
    return;
  }
  // ---- vproj part: block = keys [mt*128,+128) x cols [nt*128,+128) ----
  char* Ab = smem;
  char* Bb = smem + 16384;
  char* Img = smem + 32768;
  const int vb = (int)blockIdx.x - 1024;
  const int w = t >> 6, lane = t & 63;
  const int mt = vb >> 2, nt = vb & 3;
  const int wm = w >> 1, wn = w & 1;
  const int asub = lane & 3;
  int arow[2], acr[2];
#pragma unroll
  for (int i = 0; i < 2; ++i){
    arow[i] = (w * 2 + i) * 16 + (lane >> 2);
    acr[i]  = asub ^ ((arow[i] >> 1) & 3);
  }
  f32x4_t acc[4][4];
#pragma unroll
  for (int m = 0; m < 4; ++m)
#pragma unroll
    for (int n = 0; n < 4; ++n)
      acc[m][n] = (f32x4_t){0.f, 0.f, 0.f, 0.f};

  auto stageB = [&](int kk, int sel){
#pragma unroll
    for (int i = 0; i < 2; ++i){
      int id = w * 2 + i;
      const unsigned short* gb = WvT + (size_t)(nt * 128 + arow[i]) * 512 + kk * 32 + acr[i] * 8;
      gload16(gb, Bb + sel * 8192 + id * 1024);
    }
  };
  auto loadA = [&](int kk, float4* x, float4* y){
#pragma unroll
    for (int i = 0; i < 2; ++i){
      const float* ga = In + (size_t)(mt * 128 + arow[i]) * 512 + kk * 32 + acr[i] * 8;
      x[i] = *(const float4*)ga;
      y[i] = *(const float4*)(ga + 4);
    }
  };
  auto writeA = [&](const float4* x, const float4* y, int sel){
#pragma unroll
    for (int i = 0; i < 2; ++i){
      __align__(16) unsigned short pk[8] = {
        f2bf(x[i].x), f2bf(x[i].y), f2bf(x[i].z), f2bf(x[i].w),
        f2bf(y[i].x), f2bf(y[i].y), f2bf(y[i].z), f2bf(y[i].w)};
      *(uint4*)(Ab + sel * 8192 + arow[i] * 64 + asub * 16) = *(const uint4*)pk;
    }
  };
  {
    float4 x[2], y[2];
    loadA(0, x, y);
    stageB(0, 0);
    writeA(x, y, 0);
    __syncthreads();
  }
  for (int kk = 0; kk < 16; ++kk){
    const int cur = kk & 1;
    float4 x[2], y[2];
    if (kk < 15){
      loadA(kk + 1, x, y);
      stageB(kk + 1, cur ^ 1);
    }
    s16x8_t a[4], bf[4];
#pragma unroll
    for (int m = 0; m < 4; ++m){
      int row = wm * 64 + m * 16 + (lane & 15);
      int chn = (lane >> 4) ^ ((row >> 1) & 3);
      a[m] = *(const s16x8_t*)(Ab + cur * 8192 + row * 64 + chn * 16);
    }
#pragma unroll
    for (int n = 0; n < 4; ++n){
      int col = wn * 64 + n * 16 + (lane & 15);
      int chn = (lane >> 4) ^ ((col >> 1) & 3);
      bf[n] = *(const s16x8_t*)(Bb + cur * 8192 + col * 64 + chn * 16);
    }
#pragma unroll
    for (int m = 0; m < 4; ++m)
#pragma unroll
      for (int n = 0; n < 4; ++n)
        acc[m][n] = __builtin_amdgcn_mfma_f32_16x16x32_bf16(a[m], bf[n], acc[m][n], 0, 0, 0);
    if (kk < 15) writeA(x, y, cur ^ 1);
    __syncthreads();
  }
  // epilogue: fragment-linear 32KB chunk in LDS, linear copy out
#pragma unroll
  for (int m = 0; m < 4; ++m){
    const int ks2 = (wm * 2 + (m >> 1)) & 3;
    const int hi  = (m * 2 + ((lane >> 4) >> 1)) & 3;
    const int lo0 = ((lane >> 4) & 1) * 4;
#pragma unroll
    for (int n = 0; n < 4; ++n){
      const int g_loc = wn * 2 + (n >> 1);
      const int n2 = n & 1;
      const int cl = lane & 15;
      __align__(8) unsigned short pk2[4];
#pragma unroll
      for (int j = 0; j < 4; ++j) pk2[j] = f2bf(acc[m][n][j]);
      int boff = g_loc * 8192 + n2 * 4096 + ks2 * 1024 + hi * 256 + cl * 16 + lo0 * 2;
      *(uint2*)(Img + boff) = *(const uint2*)pk2;
    }
  }
  __syncthreads();
  const int bq = mt >> 4;
  const int kt = mt & 15;
#pragma unroll
  for (int i = 0; i < 8; ++i){
    int G = i * 256 + t;
    unsigned short* dst = Vg + (size_t)bq * 1048576 + (size_t)kt * 65536
                        + nt * 16384 + G * 8;
    *(uint4*)dst = *(const uint4*)(Img + G * 16);
  }
}

// ---------------- k_attn: 64-row x 512-col blocks, grid 256 (1/CU), 16 waves ----------------
// Round-10 structure (single vf set, no spill) + per-ks score/MFMA interleave.
__global__ __launch_bounds__(1024) void k_attn(const float* __restrict__ Qg,
                                               const float* __restrict__ Kg,
                                               const unsigned short* __restrict__ Vg,
                                               float* __restrict__ Out){
  __shared__ __align__(16) char smem[102656];
  // Klds 64KB @0 ; Pb dbuf 2x16KB @65536 ; red 4KB @98304 ; fin 256B @102400
  // epilogue img [16][520] f32 @0 overlays Klds
  const int t = threadIdx.x;
  const int g = t >> 6, lane = t & 63;     // lane = q-row
  const int b = blockIdx.x & 7;
  const int qt = blockIdx.x >> 3;
  const int qbase = qt * 64;

  float qreg[8];
  {
    const float* Qp = Qg + (size_t)(b * 2048 + qbase + lane) * 8;
    float4 a = *(const float4*)Qp;
    float4 c = *(const float4*)(Qp + 4);
    qreg[0] = a.x; qreg[1] = a.y; qreg[2] = a.z; qreg[3] = a.w;
    qreg[4] = c.x; qreg[5] = c.y; qreg[6] = c.z; qreg[7] = c.w;
  }
  const float* Kp = Kg + (size_t)b * (2048 * 8);
  const unsigned short* Vb = Vg + (size_t)b * 1048576;
  char* Klds = smem;
  char* Pb = smem + 65536;
  float* red = (float*)(smem + 98304);
  float* fin = (float*)(smem + 102400);

  // ---- stage ALL of K (64KB) once ----
#pragma unroll
  for (int i = 0; i < 4; ++i)
    gload16(Kp + (size_t)(i * 1024 + t) * 4, Klds + (i * 1024 + t) * 16);
  __syncthreads();

  // ---- prepass: exact row max of s^2 (p = (s^2)^4, same rounding path), pure VALU ----
  float amax2 = 0.f;
  {
    const float* kbase = (const float*)Klds + (g * 8) * 8;
#pragma unroll 2
    for (int tt = 0; tt < 16; ++tt){
      const float* kb = kbase + tt * 1024;
#pragma unroll
      for (int j = 0; j < 8; ++j){
        float4 k0 = *(const float4*)(kb + j * 8);
        float4 k1 = *(const float4*)(kb + j * 8 + 4);
        float s = dot8(qreg, k0, k1);
        amax2 = fmaxf(amax2, s * s);
      }
    }
  }
  red[g * 64 + lane] = amax2;
  __syncthreads();
  float am = red[lane];
#pragma unroll
  for (int s = 1; s < 16; ++s) am = fmaxf(am, red[s * 64 + lane]);
  float mreg;
  { float s4 = am * am; mreg = s4 * s4; }
  const float LOG2E = 1.44269504f;
  const float me2 = mreg * LOG2E;
  float lp = 0.f;

  const int pswz = ((g ^ (lane & 15)) << 4);

  f32x4_t acc[4][2];
#pragma unroll
  for (int mm = 0; mm < 4; ++mm)
#pragma unroll
    for (int n = 0; n < 2; ++n)
      acc[mm][n] = (f32x4_t){0.f, 0.f, 0.f, 0.f};

  // full-tile score (prologue only)
  auto score_full = [&](int tt, int sel){
    const float* kb = (const float*)Klds + (tt * 128 + g * 8) * 8;
    uint4 pkd; u32* pw = &pkd.x;
#pragma unroll
    for (int jp = 0; jp < 4; ++jp){
      float e0, e1;
#pragma unroll
      for (int h = 0; h < 2; ++h){
        const int j = jp * 2 + h;
        float4 k0 = *(const float4*)(kb + j * 8);
        float4 k1 = *(const float4*)(kb + j * 8 + 4);
        float s = dot8(qreg, k0, k1);
        float s2 = s * s; float s4 = s2 * s2; float p = s4 * s4;
        float e = __builtin_amdgcn_exp2f(fmaf(p, LOG2E, -me2));
        lp += e;
        if (h == 0) e0 = e; else e1 = e;
      }
      pw[jp] = pk2bf(e0, e1);
    }
    *(uint4*)(Pb + sel * 16384 + lane * 256 + pswz) = pkd;
  };

  score_full(0, 0);
  __syncthreads();

  // ---- main loop: per tile, interleave {2-key score chunk | a-frag reads | 8 MFMA} x4 ----
  for (int tt = 0; tt < 16; ++tt){
    const int sel = tt & 1;
    // V fragments for tile tt: 8 contiguous 1KB wave loads (issue first)
    s16x8_t vf[2][4];
    {
      const unsigned short* vb = Vb + (size_t)tt * 65536 + g * 4096 + lane * 8;
#pragma unroll
      for (int n = 0; n < 2; ++n)
#pragma unroll
        for (int ks = 0; ks < 4; ++ks)
          vf[n][ks] = *(const s16x8_t*)(vb + n * 2048 + ks * 512);
    }
    const bool more = (tt + 1 < 16);
    const float* kb = (const float*)Klds + (((tt + 1) & 15) * 128 + g * 8) * 8;
    uint4 pkd; u32* pw = &pkd.x;
#pragma unroll
    for (int ks = 0; ks < 4; ++ks){
      // score chunk: 2 keys of tile tt+1 (VALU) — mixes with ds/MFMA below
      if (more){
        float e0, e1;
#pragma unroll
        for (int h = 0; h < 2; ++h){
          const int j = ks * 2 + h;
          float4 k0 = *(const float4*)(kb + j * 8);
          float4 k1 = *(const float4*)(kb + j * 8 + 4);
          float s = dot8(qreg, k0, k1);
          float s2 = s * s; float s4 = s2 * s2; float p = s4 * s4;
          float e = __builtin_amdgcn_exp2f(fmaf(p, LOG2E, -me2));
          lp += e;
          if (h == 0) e0 = e; else e1 = e;
        }
        pw[ks] = pk2bf(e0, e1);
      }
      // A fragments for this ks slice
      s16x8_t a[4];
#pragma unroll
      for (int mm = 0; mm < 4; ++mm){
        int r = mm * 16 + (lane & 15);
        int slot = (ks * 4 + (lane >> 4)) ^ (r & 15);
        a[mm] = *(const s16x8_t*)(Pb + sel * 16384 + r * 256 + (slot << 4));
      }
      __builtin_amdgcn_s_setprio(1);
#pragma unroll
      for (int mm = 0; mm < 4; ++mm)
#pragma unroll
        for (int n = 0; n < 2; ++n)
          acc[mm][n] = __builtin_amdgcn_mfma_f32_16x16x32_bf16(a[mm], vf[n][ks], acc[mm][n], 0, 0, 0);
      __builtin_amdgcn_s_setprio(0);
    }
    if (more)
      *(uint4*)(Pb + (sel ^ 1) * 16384 + lane * 256 + pswz) = pkd;
    __syncthreads();
  }

  // ---- softmax denominator ----
  red[g * 64 + lane] = lp;
  __syncthreads();
  if (t < 64){
    float s = red[t];
#pragma unroll
    for (int s2 = 1; s2 < 16; ++s2) s += red[s2 * 64 + t];
    fin[t] = 1.f / s;
  }
  __syncthreads();

  // ---- epilogue: 4 rounds of 16 rows x 512 cols via LDS transpose (img overlays Klds) ----
  float* img = (float*)smem;
#pragma unroll
  for (int mm = 0; mm < 4; ++mm){
    float linv[4];
#pragma unroll
    for (int j = 0; j < 4; ++j)
      linv[j] = fin[mm * 16 + ((lane >> 4) << 2) + j];
#pragma unroll
    for (int n = 0; n < 2; ++n){
      int colL = g * 32 + n * 16 + (lane & 15);
#pragma unroll
      for (int j = 0; j < 4; ++j){
        int r16 = ((lane >> 4) << 2) + j;
        img[r16 * 520 + colL] = acc[mm][n][j] * linv[j];
      }
    }
    __syncthreads();
#pragma unroll
    for (int i = 0; i < 2; ++i){
      int f4 = i * 1024 + t;
      int r16 = f4 >> 7, c4 = f4 & 127;
      float4 v = *(const float4*)(img + r16 * 520 + c4 * 4);
      *(float4*)(Out + (size_t)(b * 2048 + qbase + mm * 16 + r16) * 512 + c4 * 4) = v;
    }
    __syncthreads();
  }
}

extern "C" void kernel_launch(void* const* d_in, const int* in_sizes, int n_in,
                              void* d_out, int out_size, void* d_ws, size_t ws_size,
                              hipStream_t stream){
  const float* In = (const float*)d_in[0];
  const float* Wq = (const float*)d_in[1];
  const float* Wk = (const float*)d_in[2];
  const float* Wv = (const float*)d_in[3];
  // power (d_in[4]) is the constant 8; hardcoded as three squarings.
  char* ws = (char*)d_ws;
  unsigned short* WvT = (unsigned short*)(ws);
  float* Q            = (float*)(ws + 524288);
  float* K            = (float*)(ws + 1048576);
  unsigned short* Vg  = (unsigned short*)(ws + 1572864);
  float* Out = (float*)d_out;

  hipLaunchKernelGGL(k_wvT,   dim3(64),   dim3(256),  0, stream, Wv, WvT);
  hipLaunchKernelGGL(k_fused, dim3(1536), dim3(256),  0, stream, In, Wq, Wk, WvT, Q, K, Vg);
  hipLaunchKernelGGL(k_attn,  dim3(256),  dim3(1024), 0, stream, Q, K, Vg, Out);
}